// Round 5
// baseline (281.351 us; speedup 1.0000x reference)
//
#include <hip/hip_runtime.h>

#define B_DIM 4096
#define K_TOT 2048   // IN + H
#define H_DIM 1024

typedef short bf16x8 __attribute__((ext_vector_type(8)));
typedef float f32x4 __attribute__((ext_vector_type(4)));
typedef unsigned short u16x8 __attribute__((ext_vector_type(8)));

typedef __attribute__((address_space(1))) const unsigned gas_u32;
typedef __attribute__((address_space(3))) unsigned las_u32;

static __device__ __forceinline__ unsigned short f2bf(float f) {
  union { float f; unsigned u; } v; v.f = f;
  unsigned r = v.u + 0x7FFF + ((v.u >> 16) & 1);  // RNE
  return (unsigned short)(r >> 16);
}

// ---------------- pack A and W into per-(panel, k-tile) LDS-image order ----------------
// A_pk: [by 0..15][half 0..63][v 0..1023] x 8 bf16.  half = kt*2+kh.
//   image slot v -> row r=v>>2, slot p=v&3, k-group g = p ^ ((r>>1)&3)  (XOR swizzle
//   PRE-APPLIED so gemm staging is a pure linear 16KB copy).
//   data = A[by*256+r][half*32 + g*8 .. +8)   (A = [x | h] concat on k)
// W_pk: same image per bx panel; packed row r encodes (ng,gate,c):
//   gate=(r>>4)&3, ng=r>>6, c=r&15, j = bx*64+ng*16+c  -> MFMA frag ni == gate,
//   so the LSTM pointwise has all 4 gates of (row,j) in one lane's accumulators.
__global__ void pack_all(const float* __restrict__ x, const float* __restrict__ hp,
                         const float* __restrict__ W0, const float* __restrict__ W1,
                         const float* __restrict__ W2, const float* __restrict__ W3,
                         const float* __restrict__ W4, const float* __restrict__ W5,
                         const float* __restrict__ W6, const float* __restrict__ W7,
                         u16x8* __restrict__ A, u16x8* __restrict__ Wc) {
  const int t = blockIdx.x * blockDim.x + threadIdx.x;
  const int NA = 1 << 20;   // 1048576 granules (16B) for A
  const float* src;
  u16x8* dst;
  if (t < NA) {
    int by = t >> 16;              // 65536 granules per 1MB panel
    int rem = t & 65535;
    int half = rem >> 10;          // 1024 granules per 16KB half-tile
    int v = rem & 1023;
    int r = v >> 2;
    int g = (v & 3) ^ ((r >> 1) & 3);
    int k = half * 32 + g * 8;     // k within [0,2048), 8-aligned (never crosses x/h seam)
    int row = by * 256 + r;
    src = (k < 1024) ? (x + row * 1024 + k) : (hp + row * 1024 + (k - 1024));
    dst = A + t;
  } else {
    int u = t - NA;
    int bx = u >> 16;
    int rem = u & 65535;
    int half = rem >> 10;
    int v = rem & 1023;
    int r = v >> 2;
    int g = (v & 3) ^ ((r >> 1) & 3);
    int k = half * 32 + g * 8;
    int gate = (r >> 4) & 3;
    int j = bx * 64 + (r >> 6) * 16 + (r & 15);
    int s = (k < 1024) ? gate : gate + 4;   // x-half -> Wx gate, h-half -> Wh gate
    const float* base =
        (s == 0) ? W0 : (s == 1) ? W1 : (s == 2) ? W2 : (s == 3) ? W3 :
        (s == 4) ? W4 : (s == 5) ? W5 : (s == 6) ? W6 : W7;
    src = base + j * 1024 + (k & 1023);
    dst = Wc + u;
  }
  float4 lo = *(const float4*)src;
  float4 hi = *(const float4*)(src + 4);
  u16x8 v8;
  v8[0] = f2bf(lo.x); v8[1] = f2bf(lo.y); v8[2] = f2bf(lo.z); v8[3] = f2bf(lo.w);
  v8[4] = f2bf(hi.x); v8[5] = f2bf(hi.y); v8[6] = f2bf(hi.z); v8[7] = f2bf(hi.w);
  *dst = v8;
}

static __device__ __forceinline__ float sigm(float x) {
  return 1.0f / (1.0f + __expf(-x));
}
static __device__ __forceinline__ float tanh_fast(float x) {
  x = fminf(fmaxf(x, -15.f), 15.f);
  float t = __expf(-2.0f * x);
  return (1.0f - t) / (1.0f + t);
}

// ------------- 256x256 8-phase counted-vmcnt GEMM + fused LSTM epilogue -------------
// Structure as round 2/4 (passed twice). This round:
//  * XCD swizzle: hardware XCD = linear_id mod 8; we choose (bx,by) so each XCD gets
//    a 4x8 rectangle -> 4 A-panels + 8 W-panels per XCD L2 (was 16 A + 2 W) ->
//    L3->L2 replication traffic 144 -> 96 MB, both streams' windows L2-resident.
//  * Single vmcnt(4) guard per K-tile at phase 1 (m201 cadence). Safety: guard at
//    tile kt p1 has issued through half 4kt+7, leaves <=2 halves pending -> done
//    through half 4kt+5; covers p2/p3 reads (halves 4kt+2,3) and next tile's p0/p1
//    reads (4kt+4,5) with margin. Tail: tile 30 G4 (issued 127 -> done 125),
//    tile 31 p1 G0 -> all staged.
//  * cp preloaded into 32 VGPRs before staging (oldest loads drain in the prologue
//    vmcnt(8)) -> epilogue tail is write-only.
__global__ __launch_bounds__(512, 2) void gemm_lstm(
    const unsigned short* __restrict__ A,   // packed per-(by, half) LDS image
    const unsigned short* __restrict__ W,   // packed per-(bx, half) LDS image
    const float* __restrict__ cp,
    const float* __restrict__ bii, const float* __restrict__ bif,
    const float* __restrict__ big, const float* __restrict__ bio,
    float* __restrict__ out) {
  extern __shared__ char lds[];   // 131072 B
  const int tid = threadIdx.x;
  const int w = tid >> 6;
  const int lane = tid & 63;
  const int wm = w >> 2;          // 0..1 : M half
  const int ng = w & 3;           // 0..3 : N quarter

  // XCD-aware swizzle: hardware XCD = n mod 8; give XCD x the 4x8 rect
  // bx in [4*(x&3), +4), by in [8*(x>>2), +8). Bijective over the 16x16 grid.
  const int nblk = blockIdx.y * 16 + blockIdx.x;
  const int xcd = nblk & 7;
  const int ii = nblk >> 3;                 // 0..31 within-XCD index
  const int bx = ((xcd & 3) << 2) | (ii & 3);
  const int by = ((xcd >> 2) << 3) | (ii >> 2);

  f32x4 acc[8][4];
#pragma unroll
  for (int i = 0; i < 8; ++i)
#pragma unroll
    for (int n = 0; n < 4; ++n)
      acc[i][n] = (f32x4){0.f, 0.f, 0.f, 0.f};

  // panel bases (1MB = 524288 elems each)
  const unsigned short* Ap = A + (size_t)by * 524288;
  const unsigned short* Wp = W + (size_t)bx * 524288;

  // ---- fragment-read constants
  const int fr = lane & 15;
  const int gg = lane >> 4;
  const int aoff = fr * 64 + ((gg ^ ((fr >> 1) & 3)) << 4);
  const int wmoff = wm << 13;     // wm*128 rows * 64B
  const int ngoff = ng << 12;     // ng*64 rows * 64B

  // ---- epilogue coordinates (needed early for cp preload)
  const int ccol = lane & 15;
  const int crow = (lane >> 4) << 2;
  const int j = (bx << 6) + (ng << 4) + ccol;
  const int row0 = (by << 8) + (wm << 7) + crow;
  const long BH = (long)B_DIM * H_DIM;

  // ---- cp preload: issued BEFORE staging -> oldest in vmcnt order, drained by the
  // prologue vmcnt(8); sit in VGPRs until the epilogue (tail becomes write-only).
  const float bi = bii[j];
  const float bff = bif[j];
  const float bg = big[j];
  const float bo = bio[j];
  float cpr[8][4];
#pragma unroll
  for (int mi = 0; mi < 8; ++mi)
#pragma unroll
    for (int reg = 0; reg < 4; ++reg)
      cpr[mi][reg] = cp[(long)(row0 + mi * 16 + reg) * H_DIM + j];

  bf16x8 bfr[4];

#define STAGE(H)                                                                      \
  {                                                                                   \
    const int H_ = (H);                                                               \
    char* dst_ = lds + (((H_ >> 2) & 1) << 16) + ((H_ & 1) << 15) +                   \
                 (((H_ >> 1) & 1) << 14);                                             \
    const unsigned short* s_ =                                                        \
        ((H_ & 1) ? Wp : Ap) + ((((H_ >> 2) << 1) | ((H_ >> 1) & 1)) * 8192);         \
    __builtin_amdgcn_global_load_lds((gas_u32*)(s_ + (size_t)tid * 8),                \
                                     (las_u32*)(dst_ + tid * 16), 16, 0, 0);          \
    __builtin_amdgcn_global_load_lds((gas_u32*)(s_ + (size_t)(tid + 512) * 8),        \
                                     (las_u32*)(dst_ + (tid + 512) * 16), 16, 0, 0);  \
  }

#define G4 asm volatile("s_waitcnt vmcnt(4)" ::: "memory")
#define G0 asm volatile("s_waitcnt vmcnt(0)" ::: "memory")
#define GN ((void)0)

#define DO_PHASE(P, KT, GUARD, DOSTAGE)                                        \
  {                                                                            \
    const char* lA_ = ldsbuf + ((P) >> 1) * 16384;                             \
    const char* lB_ = ldsbuf + 32768 + ((P) >> 1) * 16384;                     \
    bf16x8 af_[4];                                                             \
    _Pragma("unroll")                                                          \
    for (int i_ = 0; i_ < 4; ++i_)                                             \
      af_[i_] = *(const bf16x8*)(lA_ + wmoff + (((P) & 1) * 4 + i_) * 1024 + aoff); \
    if (((P) & 1) == 0) {                                                      \
      _Pragma("unroll")                                                        \
      for (int n_ = 0; n_ < 4; ++n_)                                           \
        bfr[n_] = *(const bf16x8*)(lB_ + ngoff + n_ * 1024 + aoff);            \
    }                                                                          \
    if (DOSTAGE) STAGE((KT) * 4 + (P) + 6);                                    \
    GUARD;                                                                     \
    __builtin_amdgcn_s_barrier();                                              \
    asm volatile("s_waitcnt lgkmcnt(0)" ::: "memory");                         \
    __builtin_amdgcn_sched_barrier(0);                                         \
    __builtin_amdgcn_s_setprio(1);                                             \
    _Pragma("unroll")                                                          \
    for (int i_ = 0; i_ < 4; ++i_) {                                           \
      _Pragma("unroll")                                                        \
      for (int n_ = 0; n_ < 4; ++n_)                                           \
        acc[((P) & 1) * 4 + i_][n_] = __builtin_amdgcn_mfma_f32_16x16x32_bf16( \
            af_[i_], bfr[n_], acc[((P) & 1) * 4 + i_][n_], 0, 0, 0);           \
    }                                                                          \
    __builtin_amdgcn_s_setprio(0);                                             \
    __builtin_amdgcn_s_barrier();                                              \
  }

  // ---- prologue: stage halves 0..5; vmcnt(8) drains all cp loads (oldest) plus
  // the 4 oldest stage loads -> halves 0,1 resident.
  STAGE(0); STAGE(1); STAGE(2); STAGE(3); STAGE(4); STAGE(5);
  asm volatile("s_waitcnt vmcnt(8)" ::: "memory");
  __builtin_amdgcn_s_barrier();

  // ---- main loop: tiles 0..29, single vmcnt(4) guard per tile (phase 1)
  for (int kt = 0; kt < 30; ++kt) {
    const char* ldsbuf = lds + ((kt & 1) << 16);
    DO_PHASE(0, kt, GN, 1);
    DO_PHASE(1, kt, G4, 1);
    DO_PHASE(2, kt, GN, 1);
    DO_PHASE(3, kt, GN, 1);
  }
  // tile 30 (buffer 0): stages halves 126,127 then stream ends
  {
    const char* ldsbuf = lds;
    DO_PHASE(0, 30, GN, 1);
    DO_PHASE(1, 30, G4, 1);
    DO_PHASE(2, 30, GN, 0);
    DO_PHASE(3, 30, GN, 0);
  }
  // tile 31 (buffer 1): drain all remaining staging at p1
  {
    const char* ldsbuf = lds + 65536;
    DO_PHASE(0, 31, GN, 0);
    DO_PHASE(1, 31, G0, 0);
    DO_PHASE(2, 31, GN, 0);
    DO_PHASE(3, 31, GN, 0);
  }
#undef DO_PHASE
#undef STAGE

  // ---- fused LSTM epilogue (write-only tail; cp already in VGPRs)
  // C/D layout: col=lane&15, row=(lane>>4)*4+reg  [m89/m91 verified]
#pragma unroll
  for (int mi = 0; mi < 8; ++mi) {
#pragma unroll
    for (int reg = 0; reg < 4; ++reg) {
      const int row = row0 + mi * 16 + reg;
      const long p = (long)row * H_DIM + j;
      const float cvp = cpr[mi][reg];
      const float iv = sigm(acc[mi][0][reg] + bi);
      const float fv = sigm(acc[mi][1][reg] + bff);
      const float gv = tanh_fast(acc[mi][2][reg] + bg);
      const float ov = sigm(acc[mi][3][reg] + bo);
      const float cv = fv * cvp + iv * gv;
      const float hv = ov * tanh_fast(cv);
      out[p]          = hv;
      out[BH + p]     = cv;
      out[2 * BH + p] = iv;
      out[3 * BH + p] = fv;
      out[4 * BH + p] = gv;
      out[5 * BH + p] = ov;
    }
  }
}

extern "C" void kernel_launch(void* const* d_in, const int* in_sizes, int n_in,
                              void* d_out, int out_size, void* d_ws, size_t ws_size,
                              hipStream_t stream) {
  const float* x    = (const float*)d_in[0];
  const float* h    = (const float*)d_in[1];
  const float* c    = (const float*)d_in[2];
  const float* W_ii = (const float*)d_in[3];
  const float* b_ii = (const float*)d_in[4];
  const float* W_if = (const float*)d_in[5];
  const float* b_if = (const float*)d_in[6];
  const float* W_ig = (const float*)d_in[7];
  const float* b_ig = (const float*)d_in[8];
  const float* W_io = (const float*)d_in[9];
  const float* b_io = (const float*)d_in[10];
  const float* W_hi = (const float*)d_in[11];
  const float* W_hf = (const float*)d_in[12];
  const float* W_hg = (const float*)d_in[13];
  const float* W_ho = (const float*)d_in[14];

  // workspace: A_pk bf16 16MB | W_pk bf16 16MB
  unsigned short* Abf = (unsigned short*)d_ws;
  unsigned short* Wbf = (unsigned short*)((char*)d_ws + (size_t)16 * 1024 * 1024);

  static bool s_attr = false;
  if (!s_attr) {
    hipFuncSetAttribute((const void*)gemm_lstm,
                        hipFuncAttributeMaxDynamicSharedMemorySize, 131072);
    s_attr = true;
  }

  pack_all<<<8192, 256, 0, stream>>>(x, h, W_ii, W_if, W_ig, W_io,
                                     W_hi, W_hf, W_hg, W_ho,
                                     (u16x8*)Abf, (u16x8*)Wbf);
  dim3 grid(H_DIM / 64, B_DIM / 256);   // 16 x 16 = 256 blocks = 1/CU
  gemm_lstm<<<grid, 512, 131072, stream>>>(Abf, Wbf, c, b_ii, b_if, b_ig, b_io,
                                           (float*)d_out);
}

// Round 6
// 261.864 us; speedup vs baseline: 1.0744x; 1.0744x over previous
//
#include <hip/hip_runtime.h>

#define B_DIM 4096
#define K_TOT 2048   // IN + H
#define H_DIM 1024

typedef short bf16x8 __attribute__((ext_vector_type(8)));
typedef float f32x4 __attribute__((ext_vector_type(4)));
typedef unsigned short u16x8 __attribute__((ext_vector_type(8)));

typedef __attribute__((address_space(1))) const unsigned gas_u32;
typedef __attribute__((address_space(3))) unsigned las_u32;

static __device__ __forceinline__ unsigned short f2bf(float f) {
  union { float f; unsigned u; } v; v.f = f;
  unsigned r = v.u + 0x7FFF + ((v.u >> 16) & 1);  // RNE
  return (unsigned short)(r >> 16);
}

// ---------------- pack A and W into per-(panel, k-tile) LDS-image order ----------------
// A_pk: [by 0..15][half 0..63][v 0..1023] x 8 bf16.  half = kt*2+kh.
//   image slot v -> row r=v>>2, slot p=v&3, k-group g = p ^ ((r>>1)&3)  (XOR swizzle
//   PRE-APPLIED so gemm staging is a pure linear 16KB copy).
//   data = A[by*256+r][half*32 + g*8 .. +8)   (A = [x | h] concat on k)
// W_pk: same image per bx panel; packed row r encodes (ng,gate,c):
//   gate=(r>>4)&3, ng=r>>6, c=r&15, j = bx*64+ng*16+c  -> MFMA frag ni == gate,
//   so the LSTM pointwise has all 4 gates of (row,j) in one lane's accumulators.
__global__ void pack_all(const float* __restrict__ x, const float* __restrict__ hp,
                         const float* __restrict__ W0, const float* __restrict__ W1,
                         const float* __restrict__ W2, const float* __restrict__ W3,
                         const float* __restrict__ W4, const float* __restrict__ W5,
                         const float* __restrict__ W6, const float* __restrict__ W7,
                         u16x8* __restrict__ A, u16x8* __restrict__ Wc) {
  const int t = blockIdx.x * blockDim.x + threadIdx.x;
  const int NA = 1 << 20;   // 1048576 granules (16B) for A
  const float* src;
  u16x8* dst;
  if (t < NA) {
    int by = t >> 16;              // 65536 granules per 1MB panel
    int rem = t & 65535;
    int half = rem >> 10;          // 1024 granules per 16KB half-tile
    int v = rem & 1023;
    int r = v >> 2;
    int g = (v & 3) ^ ((r >> 1) & 3);
    int k = half * 32 + g * 8;     // k within [0,2048), 8-aligned (never crosses x/h seam)
    int row = by * 256 + r;
    src = (k < 1024) ? (x + row * 1024 + k) : (hp + row * 1024 + (k - 1024));
    dst = A + t;
  } else {
    int u = t - NA;
    int bx = u >> 16;
    int rem = u & 65535;
    int half = rem >> 10;
    int v = rem & 1023;
    int r = v >> 2;
    int g = (v & 3) ^ ((r >> 1) & 3);
    int k = half * 32 + g * 8;
    int gate = (r >> 4) & 3;
    int j = bx * 64 + (r >> 6) * 16 + (r & 15);
    int s = (k < 1024) ? gate : gate + 4;   // x-half -> Wx gate, h-half -> Wh gate
    const float* base =
        (s == 0) ? W0 : (s == 1) ? W1 : (s == 2) ? W2 : (s == 3) ? W3 :
        (s == 4) ? W4 : (s == 5) ? W5 : (s == 6) ? W6 : W7;
    src = base + j * 1024 + (k & 1023);
    dst = Wc + u;
  }
  float4 lo = *(const float4*)src;
  float4 hi = *(const float4*)(src + 4);
  u16x8 v8;
  v8[0] = f2bf(lo.x); v8[1] = f2bf(lo.y); v8[2] = f2bf(lo.z); v8[3] = f2bf(lo.w);
  v8[4] = f2bf(hi.x); v8[5] = f2bf(hi.y); v8[6] = f2bf(hi.z); v8[7] = f2bf(hi.w);
  *dst = v8;
}

static __device__ __forceinline__ float sigm(float x) {
  return 1.0f / (1.0f + __expf(-x));
}
static __device__ __forceinline__ float tanh_fast(float x) {
  x = fminf(fmaxf(x, -15.f), 15.f);
  float t = __expf(-2.0f * x);
  return (1.0f - t) / (1.0f + t);
}

// ------------- 256x256 8-phase counted-vmcnt GEMM + fused LSTM epilogue -------------
// EXACT round-4 schedule (validated: 95.6us, VGPR 112, no spill) plus ONLY the
// XCD-aware block swizzle (round-5 evidence: FETCH 82.1 -> 73.4 MB).
//  * XCD swizzle: hardware XCD = linear_id mod 8; XCD x gets the 4x8 rect
//    bx in [4*(x&3),+4), by in [8*(x>>2),+8) -> per-XCD per-k-step slice working
//    set 384 KB (L2-resident), L3->L2 replication 160 -> 96 MB.
//  * Guard cadence: vmcnt(8) at phases 1 and 3 of each tile (twice-validated).
//  * NO cp preload (round-5 spill: VGPR 128 cap, WRITE +34 MB scratch traffic).
__global__ __launch_bounds__(512, 2) void gemm_lstm(
    const unsigned short* __restrict__ A,   // packed per-(by, half) LDS image
    const unsigned short* __restrict__ W,   // packed per-(bx, half) LDS image
    const float* __restrict__ cp,
    const float* __restrict__ bii, const float* __restrict__ bif,
    const float* __restrict__ big, const float* __restrict__ bio,
    float* __restrict__ out) {
  extern __shared__ char lds[];   // 131072 B
  const int tid = threadIdx.x;
  const int w = tid >> 6;
  const int lane = tid & 63;
  const int wm = w >> 2;          // 0..1 : M half
  const int ng = w & 3;           // 0..3 : N quarter

  // XCD-aware swizzle (bijective over the 16x16 grid)
  const int nblk = blockIdx.y * 16 + blockIdx.x;
  const int xcd = nblk & 7;
  const int ii = nblk >> 3;                 // 0..31 within-XCD index
  const int bx = ((xcd & 3) << 2) | (ii & 3);
  const int by = ((xcd >> 2) << 3) | (ii >> 2);

  f32x4 acc[8][4];
#pragma unroll
  for (int i = 0; i < 8; ++i)
#pragma unroll
    for (int n = 0; n < 4; ++n)
      acc[i][n] = (f32x4){0.f, 0.f, 0.f, 0.f};

  // panel bases (1MB = 524288 elems each)
  const unsigned short* Ap = A + (size_t)by * 524288;
  const unsigned short* Wp = W + (size_t)bx * 524288;

  // ---- fragment-read constants
  const int fr = lane & 15;
  const int gg = lane >> 4;
  const int aoff = fr * 64 + ((gg ^ ((fr >> 1) & 3)) << 4);
  const int wmoff = wm << 13;     // wm*128 rows * 64B
  const int ngoff = ng << 12;     // ng*64 rows * 64B

  bf16x8 bfr[4];

#define STAGE(H)                                                                      \
  {                                                                                   \
    const int H_ = (H);                                                               \
    char* dst_ = lds + (((H_ >> 2) & 1) << 16) + ((H_ & 1) << 15) +                   \
                 (((H_ >> 1) & 1) << 14);                                             \
    const unsigned short* s_ =                                                        \
        ((H_ & 1) ? Wp : Ap) + ((((H_ >> 2) << 1) | ((H_ >> 1) & 1)) * 8192);         \
    __builtin_amdgcn_global_load_lds((gas_u32*)(s_ + (size_t)tid * 8),                \
                                     (las_u32*)(dst_ + tid * 16), 16, 0, 0);          \
    __builtin_amdgcn_global_load_lds((gas_u32*)(s_ + (size_t)(tid + 512) * 8),        \
                                     (las_u32*)(dst_ + (tid + 512) * 16), 16, 0, 0);  \
  }

#define G8 asm volatile("s_waitcnt vmcnt(8)" ::: "memory")
#define G4 asm volatile("s_waitcnt vmcnt(4)" ::: "memory")
#define G0 asm volatile("s_waitcnt vmcnt(0)" ::: "memory")
#define GN ((void)0)

#define DO_PHASE(P, KT, GUARD, DOSTAGE)                                        \
  {                                                                            \
    const char* lA_ = ldsbuf + ((P) >> 1) * 16384;                             \
    const char* lB_ = ldsbuf + 32768 + ((P) >> 1) * 16384;                     \
    bf16x8 af_[4];                                                             \
    _Pragma("unroll")                                                          \
    for (int i_ = 0; i_ < 4; ++i_)                                             \
      af_[i_] = *(const bf16x8*)(lA_ + wmoff + (((P) & 1) * 4 + i_) * 1024 + aoff); \
    if (((P) & 1) == 0) {                                                      \
      _Pragma("unroll")                                                        \
      for (int n_ = 0; n_ < 4; ++n_)                                           \
        bfr[n_] = *(const bf16x8*)(lB_ + ngoff + n_ * 1024 + aoff);            \
    }                                                                          \
    if (DOSTAGE) STAGE((KT) * 4 + (P) + 6);                                    \
    GUARD;                                                                     \
    __builtin_amdgcn_s_barrier();                                              \
    asm volatile("s_waitcnt lgkmcnt(0)" ::: "memory");                         \
    __builtin_amdgcn_sched_barrier(0);                                         \
    __builtin_amdgcn_s_setprio(1);                                             \
    _Pragma("unroll")                                                          \
    for (int i_ = 0; i_ < 4; ++i_) {                                           \
      _Pragma("unroll")                                                        \
      for (int n_ = 0; n_ < 4; ++n_)                                           \
        acc[((P) & 1) * 4 + i_][n_] = __builtin_amdgcn_mfma_f32_16x16x32_bf16( \
            af_[i_], bfr[n_], acc[((P) & 1) * 4 + i_][n_], 0, 0, 0);           \
    }                                                                          \
    __builtin_amdgcn_s_setprio(0);                                             \
    __builtin_amdgcn_s_barrier();                                              \
  }

  // ---- prologue: stage halves 0..5, wait for halves 0,1 (4 halves = 8 loads in flight)
  STAGE(0); STAGE(1); STAGE(2); STAGE(3); STAGE(4); STAGE(5);
  asm volatile("s_waitcnt vmcnt(8)" ::: "memory");
  __builtin_amdgcn_s_barrier();

  // ---- main loop: tiles 0..29, steady-state vmcnt(8) at phases 1 and 3
  for (int kt = 0; kt < 30; ++kt) {
    const char* ldsbuf = lds + ((kt & 1) << 16);
    DO_PHASE(0, kt, GN, 1);
    DO_PHASE(1, kt, G8, 1);
    DO_PHASE(2, kt, GN, 1);
    DO_PHASE(3, kt, G8, 1);
  }
  // tile 30 (buffer 0): stages halves 126,127 then stream ends
  {
    const char* ldsbuf = lds;
    DO_PHASE(0, 30, GN, 1);
    DO_PHASE(1, 30, G8, 1);
    DO_PHASE(2, 30, GN, 0);
    DO_PHASE(3, 30, G4, 0);
  }
  // tile 31 (buffer 1): drain
  {
    const char* ldsbuf = lds + 65536;
    DO_PHASE(0, 31, GN, 0);
    DO_PHASE(1, 31, G0, 0);
    DO_PHASE(2, 31, GN, 0);
    DO_PHASE(3, 31, GN, 0);
  }
#undef DO_PHASE
#undef STAGE

  // ---- fused LSTM epilogue
  // C/D layout: col=lane&15, row=(lane>>4)*4+reg  [m89/m91 verified]
  // frag ni == gate; j = bx*64 + ng*16 + ccol
  const int ccol = lane & 15;
  const int crow = (lane >> 4) << 2;
  const int j = (bx << 6) + (ng << 4) + ccol;
  const float bi = bii[j];
  const float bff = bif[j];
  const float bg = big[j];
  const float bo = bio[j];
  const long BH = (long)B_DIM * H_DIM;
  const int row0 = (by << 8) + (wm << 7) + crow;
#pragma unroll
  for (int mi = 0; mi < 8; ++mi) {
#pragma unroll
    for (int reg = 0; reg < 4; ++reg) {
      const int row = row0 + mi * 16 + reg;
      const long p = (long)row * H_DIM + j;
      const float cvp = cp[p];
      const float iv = sigm(acc[mi][0][reg] + bi);
      const float fv = sigm(acc[mi][1][reg] + bff);
      const float gv = tanh_fast(acc[mi][2][reg] + bg);
      const float ov = sigm(acc[mi][3][reg] + bo);
      const float cv = fv * cvp + iv * gv;
      const float hv = ov * tanh_fast(cv);
      out[p]          = hv;
      out[BH + p]     = cv;
      out[2 * BH + p] = iv;
      out[3 * BH + p] = fv;
      out[4 * BH + p] = gv;
      out[5 * BH + p] = ov;
    }
  }
}

extern "C" void kernel_launch(void* const* d_in, const int* in_sizes, int n_in,
                              void* d_out, int out_size, void* d_ws, size_t ws_size,
                              hipStream_t stream) {
  const float* x    = (const float*)d_in[0];
  const float* h    = (const float*)d_in[1];
  const float* c    = (const float*)d_in[2];
  const float* W_ii = (const float*)d_in[3];
  const float* b_ii = (const float*)d_in[4];
  const float* W_if = (const float*)d_in[5];
  const float* b_if = (const float*)d_in[6];
  const float* W_ig = (const float*)d_in[7];
  const float* b_ig = (const float*)d_in[8];
  const float* W_io = (const float*)d_in[9];
  const float* b_io = (const float*)d_in[10];
  const float* W_hi = (const float*)d_in[11];
  const float* W_hf = (const float*)d_in[12];
  const float* W_hg = (const float*)d_in[13];
  const float* W_ho = (const float*)d_in[14];

  // workspace: A_pk bf16 16MB | W_pk bf16 16MB
  unsigned short* Abf = (unsigned short*)d_ws;
  unsigned short* Wbf = (unsigned short*)((char*)d_ws + (size_t)16 * 1024 * 1024);

  static bool s_attr = false;
  if (!s_attr) {
    hipFuncSetAttribute((const void*)gemm_lstm,
                        hipFuncAttributeMaxDynamicSharedMemorySize, 131072);
    s_attr = true;
  }

  pack_all<<<8192, 256, 0, stream>>>(x, h, W_ii, W_if, W_ig, W_io,
                                     W_hi, W_hf, W_hg, W_ho,
                                     (u16x8*)Abf, (u16x8*)Wbf);
  dim3 grid(H_DIM / 64, B_DIM / 256);   // 16 x 16 = 256 blocks = 1/CU
  gemm_lstm<<<grid, 512, 131072, stream>>>(Abf, Wbf, c, b_ii, b_if, b_ig, b_io,
                                           (float*)d_out);
}

// Round 7
// 257.839 us; speedup vs baseline: 1.0912x; 1.0156x over previous
//
#include <hip/hip_runtime.h>

#define B_DIM 4096
#define K_TOT 2048   // IN + H
#define H_DIM 1024

typedef short bf16x8 __attribute__((ext_vector_type(8)));
typedef float f32x4 __attribute__((ext_vector_type(4)));
typedef unsigned short u16x8 __attribute__((ext_vector_type(8)));

typedef __attribute__((address_space(1))) const unsigned gas_u32;
typedef __attribute__((address_space(3))) unsigned las_u32;

static __device__ __forceinline__ unsigned short f2bf(float f) {
  union { float f; unsigned u; } v; v.f = f;
  unsigned r = v.u + 0x7FFF + ((v.u >> 16) & 1);  // RNE
  return (unsigned short)(r >> 16);
}

// ---------------- pack A and W into per-(panel, k-tile) LDS-image order ----------------
// Image layout (unchanged, gemm-validated): granule (panel, half, v), v -> row r=v>>2,
// slot p=v&3, k-group g = p ^ ((r>>1)&3), data = 8 bf16 at k = half*32+g*8.
// ROUND-7 FIX: thread <- (panel, row, k8) instead of <- output granule. Reads are now
// row-sequential float4 pairs (fully coalesced; round-2..6 version gathered scattered
// 64B segments at 4KB stride). Writes: v = r*4 + ((k8&3)^((r>>1)&3)) -> permuted
// within each 64B granule-quad; adjacent rows' half-lines written by consecutive
// iterations of the same wave -> L2 write-merge. Bytes bit-identical to round 6.
__global__ void pack_all(const float* __restrict__ x, const float* __restrict__ hp,
                         const float* __restrict__ W0, const float* __restrict__ W1,
                         const float* __restrict__ W2, const float* __restrict__ W3,
                         const float* __restrict__ W4, const float* __restrict__ W5,
                         const float* __restrict__ W6, const float* __restrict__ W7,
                         u16x8* __restrict__ A, u16x8* __restrict__ Wc) {
  const int t = blockIdx.x * blockDim.x + threadIdx.x;
  const int NA = 1 << 20;   // 1048576 chunks (8 floats) for A
  const float* src;
  u16x8* dst;
  if (t < NA) {
    int by = t >> 16;               // 16 panels x 65536 chunks
    int rem = t & 65535;
    int r = rem >> 8;               // source row within panel (0..255)
    int k8 = rem & 255;             // 8-float chunk along k (0..255)
    int k = k8 << 3;
    int row = by * 256 + r;
    src = (k < 1024) ? (x + row * 1024 + k) : (hp + row * 1024 + (k - 1024));
    int p = (k8 & 3) ^ ((r >> 1) & 3);
    dst = A + ((size_t)by << 16) + ((k8 >> 2) << 10) + (r << 2) + p;
  } else {
    int u = t - NA;
    int bx = u >> 16;
    int rem = u & 65535;
    int r = rem >> 8;               // packed W row within panel (0..255)
    int k8 = rem & 255;
    int k = k8 << 3;
    int gate = (r >> 4) & 3;
    int j = bx * 64 + (r >> 6) * 16 + (r & 15);
    int s = (k < 1024) ? gate : gate + 4;   // x-half -> Wx gate, h-half -> Wh gate
    const float* base =
        (s == 0) ? W0 : (s == 1) ? W1 : (s == 2) ? W2 : (s == 3) ? W3 :
        (s == 4) ? W4 : (s == 5) ? W5 : (s == 6) ? W6 : W7;
    src = base + j * 1024 + (k & 1023);
    int p = (k8 & 3) ^ ((r >> 1) & 3);
    dst = Wc + ((size_t)bx << 16) + ((k8 >> 2) << 10) + (r << 2) + p;
  }
  float4 lo = *(const float4*)src;
  float4 hi = *(const float4*)(src + 4);
  u16x8 v8;
  v8[0] = f2bf(lo.x); v8[1] = f2bf(lo.y); v8[2] = f2bf(lo.z); v8[3] = f2bf(lo.w);
  v8[4] = f2bf(hi.x); v8[5] = f2bf(hi.y); v8[6] = f2bf(hi.z); v8[7] = f2bf(hi.w);
  *dst = v8;
}

static __device__ __forceinline__ float sigm(float x) {
  return 1.0f / (1.0f + __expf(-x));
}
static __device__ __forceinline__ float tanh_fast(float x) {
  x = fminf(fmaxf(x, -15.f), 15.f);
  float t = __expf(-2.0f * x);
  return (1.0f - t) / (1.0f + t);
}

// ------------- 256x256 8-phase counted-vmcnt GEMM + fused LSTM epilogue -------------
// Round-6 schedule (validated 94us) + XCD swizzle (FETCH 82->57.6 MB). Round-7 delta:
// removed manual lgkmcnt(0)+sched_barrier(0) after barrier1 — our ds_reads are
// compiler-visible, so hipcc emits per-use lgkmcnt(4/3/1/0); on odd phases the first
// MFMA now waits on 1 read instead of 4. No ds_writes exist; vmcnt guard semantics
// unchanged -> no correctness surface.
__global__ __launch_bounds__(512, 2) void gemm_lstm(
    const unsigned short* __restrict__ A,   // packed per-(by, half) LDS image
    const unsigned short* __restrict__ W,   // packed per-(bx, half) LDS image
    const float* __restrict__ cp,
    const float* __restrict__ bii, const float* __restrict__ bif,
    const float* __restrict__ big, const float* __restrict__ bio,
    float* __restrict__ out) {
  extern __shared__ char lds[];   // 131072 B
  const int tid = threadIdx.x;
  const int w = tid >> 6;
  const int lane = tid & 63;
  const int wm = w >> 2;          // 0..1 : M half
  const int ng = w & 3;           // 0..3 : N quarter

  // XCD-aware swizzle (bijective over the 16x16 grid): XCD x gets rect
  // bx in [4*(x&3),+4), by in [8*(x>>2),+8)
  const int nblk = blockIdx.y * 16 + blockIdx.x;
  const int xcd = nblk & 7;
  const int ii = nblk >> 3;                 // 0..31 within-XCD index
  const int bx = ((xcd & 3) << 2) | (ii & 3);
  const int by = ((xcd >> 2) << 3) | (ii >> 2);

  f32x4 acc[8][4];
#pragma unroll
  for (int i = 0; i < 8; ++i)
#pragma unroll
    for (int n = 0; n < 4; ++n)
      acc[i][n] = (f32x4){0.f, 0.f, 0.f, 0.f};

  // panel bases (1MB = 524288 elems each)
  const unsigned short* Ap = A + (size_t)by * 524288;
  const unsigned short* Wp = W + (size_t)bx * 524288;

  // ---- fragment-read constants
  const int fr = lane & 15;
  const int gg = lane >> 4;
  const int aoff = fr * 64 + ((gg ^ ((fr >> 1) & 3)) << 4);
  const int wmoff = wm << 13;     // wm*128 rows * 64B
  const int ngoff = ng << 12;     // ng*64 rows * 64B

  bf16x8 bfr[4];

#define STAGE(H)                                                                      \
  {                                                                                   \
    const int H_ = (H);                                                               \
    char* dst_ = lds + (((H_ >> 2) & 1) << 16) + ((H_ & 1) << 15) +                   \
                 (((H_ >> 1) & 1) << 14);                                             \
    const unsigned short* s_ =                                                        \
        ((H_ & 1) ? Wp : Ap) + ((((H_ >> 2) << 1) | ((H_ >> 1) & 1)) * 8192);         \
    __builtin_amdgcn_global_load_lds((gas_u32*)(s_ + (size_t)tid * 8),                \
                                     (las_u32*)(dst_ + tid * 16), 16, 0, 0);          \
    __builtin_amdgcn_global_load_lds((gas_u32*)(s_ + (size_t)(tid + 512) * 8),        \
                                     (las_u32*)(dst_ + (tid + 512) * 16), 16, 0, 0);  \
  }

#define G8 asm volatile("s_waitcnt vmcnt(8)" ::: "memory")
#define G4 asm volatile("s_waitcnt vmcnt(4)" ::: "memory")
#define G0 asm volatile("s_waitcnt vmcnt(0)" ::: "memory")
#define GN ((void)0)

#define DO_PHASE(P, KT, GUARD, DOSTAGE)                                        \
  {                                                                            \
    const char* lA_ = ldsbuf + ((P) >> 1) * 16384;                             \
    const char* lB_ = ldsbuf + 32768 + ((P) >> 1) * 16384;                     \
    bf16x8 af_[4];                                                             \
    _Pragma("unroll")                                                          \
    for (int i_ = 0; i_ < 4; ++i_)                                             \
      af_[i_] = *(const bf16x8*)(lA_ + wmoff + (((P) & 1) * 4 + i_) * 1024 + aoff); \
    if (((P) & 1) == 0) {                                                      \
      _Pragma("unroll")                                                        \
      for (int n_ = 0; n_ < 4; ++n_)                                           \
        bfr[n_] = *(const bf16x8*)(lB_ + ngoff + n_ * 1024 + aoff);            \
    }                                                                          \
    if (DOSTAGE) STAGE((KT) * 4 + (P) + 6);                                    \
    GUARD;                                                                     \
    __builtin_amdgcn_s_barrier();                                              \
    __builtin_amdgcn_s_setprio(1);                                             \
    _Pragma("unroll")                                                          \
    for (int i_ = 0; i_ < 4; ++i_) {                                           \
      _Pragma("unroll")                                                        \
      for (int n_ = 0; n_ < 4; ++n_)                                           \
        acc[((P) & 1) * 4 + i_][n_] = __builtin_amdgcn_mfma_f32_16x16x32_bf16( \
            af_[i_], bfr[n_], acc[((P) & 1) * 4 + i_][n_], 0, 0, 0);           \
    }                                                                          \
    __builtin_amdgcn_s_setprio(0);                                             \
    __builtin_amdgcn_s_barrier();                                              \
  }

  // ---- prologue: stage halves 0..5, wait for halves 0,1 (4 halves = 8 loads in flight)
  STAGE(0); STAGE(1); STAGE(2); STAGE(3); STAGE(4); STAGE(5);
  asm volatile("s_waitcnt vmcnt(8)" ::: "memory");
  __builtin_amdgcn_s_barrier();

  // ---- main loop: tiles 0..29, steady-state vmcnt(8) at phases 1 and 3
  for (int kt = 0; kt < 30; ++kt) {
    const char* ldsbuf = lds + ((kt & 1) << 16);
    DO_PHASE(0, kt, GN, 1);
    DO_PHASE(1, kt, G8, 1);
    DO_PHASE(2, kt, GN, 1);
    DO_PHASE(3, kt, G8, 1);
  }
  // tile 30 (buffer 0): stages halves 126,127 then stream ends
  {
    const char* ldsbuf = lds;
    DO_PHASE(0, 30, GN, 1);
    DO_PHASE(1, 30, G8, 1);
    DO_PHASE(2, 30, GN, 0);
    DO_PHASE(3, 30, G4, 0);
  }
  // tile 31 (buffer 1): drain
  {
    const char* ldsbuf = lds + 65536;
    DO_PHASE(0, 31, GN, 0);
    DO_PHASE(1, 31, G0, 0);
    DO_PHASE(2, 31, GN, 0);
    DO_PHASE(3, 31, GN, 0);
  }
#undef DO_PHASE
#undef STAGE

  // ---- fused LSTM epilogue
  // C/D layout: col=lane&15, row=(lane>>4)*4+reg  [m89/m91 verified]
  // frag ni == gate; j = bx*64 + ng*16 + ccol
  const int ccol = lane & 15;
  const int crow = (lane >> 4) << 2;
  const int j = (bx << 6) + (ng << 4) + ccol;
  const float bi = bii[j];
  const float bff = bif[j];
  const float bg = big[j];
  const float bo = bio[j];
  const long BH = (long)B_DIM * H_DIM;
  const int row0 = (by << 8) + (wm << 7) + crow;
#pragma unroll
  for (int mi = 0; mi < 8; ++mi) {
#pragma unroll
    for (int reg = 0; reg < 4; ++reg) {
      const int row = row0 + mi * 16 + reg;
      const long p = (long)row * H_DIM + j;
      const float cvp = cp[p];
      const float iv = sigm(acc[mi][0][reg] + bi);
      const float fv = sigm(acc[mi][1][reg] + bff);
      const float gv = tanh_fast(acc[mi][2][reg] + bg);
      const float ov = sigm(acc[mi][3][reg] + bo);
      const float cv = fv * cvp + iv * gv;
      const float hv = ov * tanh_fast(cv);
      out[p]          = hv;
      out[BH + p]     = cv;
      out[2 * BH + p] = iv;
      out[3 * BH + p] = fv;
      out[4 * BH + p] = gv;
      out[5 * BH + p] = ov;
    }
  }
}

extern "C" void kernel_launch(void* const* d_in, const int* in_sizes, int n_in,
                              void* d_out, int out_size, void* d_ws, size_t ws_size,
                              hipStream_t stream) {
  const float* x    = (const float*)d_in[0];
  const float* h    = (const float*)d_in[1];
  const float* c    = (const float*)d_in[2];
  const float* W_ii = (const float*)d_in[3];
  const float* b_ii = (const float*)d_in[4];
  const float* W_if = (const float*)d_in[5];
  const float* b_if = (const float*)d_in[6];
  const float* W_ig = (const float*)d_in[7];
  const float* b_ig = (const float*)d_in[8];
  const float* W_io = (const float*)d_in[9];
  const float* b_io = (const float*)d_in[10];
  const float* W_hi = (const float*)d_in[11];
  const float* W_hf = (const float*)d_in[12];
  const float* W_hg = (const float*)d_in[13];
  const float* W_ho = (const float*)d_in[14];

  // workspace: A_pk bf16 16MB | W_pk bf16 16MB
  unsigned short* Abf = (unsigned short*)d_ws;
  unsigned short* Wbf = (unsigned short*)((char*)d_ws + (size_t)16 * 1024 * 1024);

  static bool s_attr = false;
  if (!s_attr) {
    hipFuncSetAttribute((const void*)gemm_lstm,
                        hipFuncAttributeMaxDynamicSharedMemorySize, 131072);
    s_attr = true;
  }

  pack_all<<<8192, 256, 0, stream>>>(x, h, W_ii, W_if, W_ig, W_io,
                                     W_hi, W_hf, W_hg, W_ho,
                                     (u16x8*)Abf, (u16x8*)Wbf);
  dim3 grid(H_DIM / 64, B_DIM / 256);   // 16 x 16 = 256 blocks = 1/CU
  gemm_lstm<<<grid, 512, 131072, stream>>>(Abf, Wbf, c, b_ii, b_if, b_ig, b_io,
                                           (float*)d_out);
}